// Round 1
// baseline (341.785 us; speedup 1.0000x reference)
//
#include <hip/hip_runtime.h>

#define SEQ    256
#define FEAT   768
#define WIN    3
#define FILT   6
#define KTOT   (WIN * FEAT)      // 2304
#define WELEMS (KTOT * FILT)     // 13824 floats = 55296 B LDS
#define NB     8                 // batches per wave-group
#define BLOCK  1024
#define NWAVES (BLOCK / 64)      // 16
#define BATCH  256
#define NGROUPS (BATCH / NB)     // 32

// One block per sequence position s. W[s] (55 KB) staged in LDS once,
// reused by all 256 batches. Each wave handles 8 batches at a time so
// each LDS W-read feeds 8 FMAs (LDS traffic /8). 4 waves/SIMD for latency
// hiding: __launch_bounds__(1024,4) => 1 block/CU, VGPR cap 128.
__global__ __launch_bounds__(BLOCK, 4)
void pos_linear_kernel(const float* __restrict__ x,
                       const float* __restrict__ W,
                       const float* __restrict__ bias,
                       float* __restrict__ out) {
    __shared__ float wlds[WELEMS];
    const int s   = blockIdx.x;
    const int tid = threadIdx.x;

    // Stage W[s] -> LDS, float4 coalesced (13824 floats = 3456 float4)
    {
        const float4* src = (const float4*)(W + (size_t)s * WELEMS);
        float4*       dst = (float4*)wlds;
        for (int i = tid; i < WELEMS / 4; i += BLOCK) dst[i] = src[i];
    }
    __syncthreads();

    const int lane = tid & 63;
    const int wave = tid >> 6;

    for (int g = wave; g < NGROUPS; g += NWAVES) {
        const int b0 = g * NB;

        float acc[NB][FILT];
        #pragma unroll
        for (int nb = 0; nb < NB; ++nb)
            #pragma unroll
            for (int o = 0; o < FILT; ++o) acc[nb][o] = 0.f;

        #pragma unroll
        for (int w = 0; w < WIN; ++w) {
            const int r = s - 1 + w;          // original input row
            if (r < 0 || r >= SEQ) continue;  // zero-pad: skip (wave-uniform)
            const float* xrow0 = x + ((size_t)b0 * SEQ + r) * FEAT;
            const float* wbase = wlds + w * FEAT * FILT;

            for (int i = 0; i < FEAT / 64; ++i) {   // 12 iterations
                const int f = lane + 64 * i;

                float wv[FILT];                      // 24 B/lane, stride-6 dwords
                #pragma unroll                       // -> 2-way bank alias (free)
                for (int o = 0; o < FILT; ++o) wv[o] = wbase[f * FILT + o];

                float xv[NB];                        // coalesced dword loads
                #pragma unroll
                for (int nb = 0; nb < NB; ++nb)
                    xv[nb] = xrow0[(size_t)nb * SEQ * FEAT + f];

                #pragma unroll
                for (int nb = 0; nb < NB; ++nb)
                    #pragma unroll
                    for (int o = 0; o < FILT; ++o)
                        acc[nb][o] = fmaf(xv[nb], wv[o], acc[nb][o]);
            }
        }

        // Butterfly reduce all 48 partials across the 64 lanes.
        float vals[NB * FILT];
        #pragma unroll
        for (int nb = 0; nb < NB; ++nb)
            #pragma unroll
            for (int o = 0; o < FILT; ++o) vals[nb * FILT + o] = acc[nb][o];

        #pragma unroll
        for (int m = 1; m < 64; m <<= 1) {
            #pragma unroll
            for (int i = 0; i < NB * FILT; ++i)
                vals[i] += __shfl_xor(vals[i], m, 64);
        }

        // Every lane now holds all 48 sums; lane L (<48) selects sum #L.
        if (lane < NB * FILT) {
            float v = vals[0];
            #pragma unroll
            for (int i = 1; i < NB * FILT; ++i) v = (lane == i) ? vals[i] : v;
            const int nb = lane / FILT;
            const int o  = lane - nb * FILT;
            v += bias[s * FILT + o];
            v = v > 0.f ? v : 0.f;
            out[((size_t)(b0 + nb) * SEQ + s) * FILT + o] = v;
        }
    }
}

extern "C" void kernel_launch(void* const* d_in, const int* in_sizes, int n_in,
                              void* d_out, int out_size, void* d_ws, size_t ws_size,
                              hipStream_t stream) {
    const float* x  = (const float*)d_in[0];  // (256, 256, 768) fp32
    const float* W  = (const float*)d_in[1];  // (256, 2304, 6) fp32
    const float* b  = (const float*)d_in[2];  // (256, 6) fp32
    float*       out = (float*)d_out;         // (256, 256, 6) fp32
    (void)in_sizes; (void)n_in; (void)out_size; (void)d_ws; (void)ws_size;
    pos_linear_kernel<<<SEQ, BLOCK, 0, stream>>>(x, W, b, out);
}